// Round 11
// baseline (283.618 us; speedup 1.0000x reference)
//
#include <hip/hip_runtime.h>

// CTC batch cost (keras ctc_batch_cost semantics), forward only.
// B=512, T=512, C=128 (blank=127), L=32, S=65.
//
// Round-11: COLUMN-COMPACTION. The recurrence touches only 33 of 128
// columns (32 labels + blank). Phase 1: stream the block's 256 KB batch
// slice 100% coalesced (global_load_lds, 2-deep 4-row ring, counted vmcnt)
// and compact the 33 columns into LDS table[512][36] (73.7 KB; block total
// 78 KB -> 2 blocks/CU). Phase 2: r9 fwd/bwd-split recurrence verbatim,
// loadQ replaced by conflict-free LDS gather (odd lanes = 32 distinct
// banks, even lanes = broadcast; 2-way is free). ZERO divergent VMEM.
// Evidence: r8 split null (per-CU scattered count invariant) + r10 warm
// null (residency irrelevant) => per-CU divergent-VMEM processing is the
// surviving bottleneck. Phase-2 math order r9-byte-identical (absmax 4.0).

#define EPSF 1e-7f

constexpr int C_    = 128;
constexpr int L_    = 32;
constexpr int NSLOT = 36;   // 33 used: slots 0..31 = labels, 32 = blank

// lane j -> value of lane j-1; lane 0 -> 0.  (DPP wave_shr:1, bound_ctrl=0-fill)
__device__ __forceinline__ float wshr1(float x) {
    return __int_as_float(
        __builtin_amdgcn_mov_dpp(__float_as_int(x), 0x138, 0xf, 0xf, true));
}

// Exponent of strided wave max of v (lanes 3,7,...,63). Positive floats:
// int-max of bit patterns == bit pattern of float max; only exponent used.
// 27 = biased exponent of the 1e-30 dead-sample guard (self-corrects).
__device__ __forceinline__ int sample_eb(float v) {
    int mb = __builtin_amdgcn_readlane(__float_as_int(v), 3);
#pragma unroll
    for (int i = 1; i < 16; ++i) {
        const int t = __builtin_amdgcn_readlane(__float_as_int(v), 4 * i + 3);
        mb = (t > mb) ? t : mb;
    }
    const int eb = (int)((unsigned)mb >> 23);
    return (eb > 27) ? eb : 27;
}

__device__ __forceinline__ void gl16(const float* gp, float* lp) {
    // Each lane copies 16B from its own global address to
    // (wave-uniform LDS base) + lane*16.
    __builtin_amdgcn_global_load_lds(
        (const __attribute__((address_space(1))) void*)gp,
        (__attribute__((address_space(3))) void*)lp,
        16, 0, 0);
}

__launch_bounds__(128)
__global__ void ctc_loss_kernel(const int* __restrict__ y_true,
                                const float* __restrict__ y_pred,
                                float* __restrict__ out) {
    __shared__ float table[512][NSLOT];   // 73,728 B compact column table
    __shared__ float ring[8][128];        // 4,096 B staging ring (2 x 4 rows)
    __shared__ float shR[65];             // reversed wave's alpha'
    __shared__ int   shE;                 // reversed wave's exponent total

    const int b    = blockIdx.x;
    const int tid  = threadIdx.x;
    const int lane = tid & 63;
    const int w    = tid >> 6;   // 0 = forward, 1 = reversed

    const float* bb  = y_pred + (size_t)b * 512 * C_;
    const int*   lbl = y_true + b * L_;

    // ---- phase-1 extraction params (per thread, fixed) -------------------
    // pass0: job=tid -> row_off r0=tid/36, slot s0=tid%36 (rows 0..3).
    // pass1: job=128+tid (tid<13) -> row_off 3, slot s1=20+tid (20..32).
    const int s0 = tid % NSLOT;
    const int r0 = tid / NSLOT;
    const int c0 = (s0 < 32) ? lbl[s0] : (C_ - 1);
    const int s1 = 20 + tid;
    const int c1 = (tid < 12) ? lbl[s1] : (C_ - 1);

    // ---- per-wave recurrence params --------------------------------------
    // fwd: state = lane over ext(labels); rev: ext(reversed labels).
    // slot(lane): column of state's class in the compact table.
    int   slot;
    float sg0 = 0.f;
    if (w == 0) {
        slot = (lane & 1) ? ((lane - 1) >> 1) : 32;
        if ((lane & 1) && lane >= 3) {
            const int li = (lane - 1) >> 1;
            if (lbl[li] != lbl[li - 1]) sg0 = 1.f;
        }
    } else {
        slot = (lane & 1) ? (31 - ((lane - 1) >> 1)) : 32;
        if ((lane & 1) && lane >= 3) {
            const int li = (lane - 1) >> 1;
            if (lbl[31 - li] != lbl[32 - li]) sg0 = 1.f;
        }
    }

    // ======================= PHASE 1: compaction ==========================
    // Chunk c = original rows 4c..4c+3. Wave w streams rows 4c+2w,4c+2w+1
    // (1 KB) into the ring; both waves extract all 4 rows after the wait.
    auto issue = [&](int c) {
        const int row = c * 4 + w * 2;
        gl16(bb + (size_t)row * C_ + lane * 4, &ring[row & 7][0]);
    };
    issue(0); issue(1);
#pragma clang loop unroll(disable)
    for (int c = 0; c < 128; ++c) {
        if (c < 127) asm volatile("s_waitcnt vmcnt(1)" ::: "memory");
        else         asm volatile("s_waitcnt vmcnt(0)" ::: "memory");
        __syncthreads();
        const int rb = c * 4;
        if (s0 < 33)  table[rb + r0][s0] = ring[(rb + r0) & 7][c0];
        if (tid < 13) table[rb + 3][s1]  = ring[(rb + 3) & 7][c1];
        __syncthreads();
        if (c + 2 < 128) issue(c + 2);
    }
    // All 512 rows compacted; last barrier above protects table reads.

    // ======================= PHASE 2: recurrence ==========================
    // Recursion-time t (0..255) -> original row: fwd t, rev 511-t.
    auto trow = [&](int t) { return w ? (511 - t) : t; };

    float a       = (lane < 2) ? (table[trow(0)][slot] + EPSF) : 0.f;
    float a64     = 0.f;   // state-64 sink, meaningful on lane 63 only
    int   e_total = 0;     // accumulated log2 scale (exact integer)

    auto ldsq = [&](float (&Pk)[4], int g) {
        const int t0 = 1 + 4 * g;
#pragma unroll
        for (int j = 0; j < 4; ++j) Pk[j] = table[trow(t0 + j)][slot];
    };

    // Composed 4-row update, column-0 collapsed form (r5-proven).
    auto group4 = [&](const float (&P)[4]) {
        float x = a, z = a64;
#pragma unroll
        for (int r = 0; r < 4; ++r) {
            const float q  = P[r] + EPSF;
            const float qs = wshr1(q);      // blank-column value at lane 63
            const float x1 = wshr1(x);
            const float x2 = wshr1(x1);
            z = (z + x) * qs;               // state-64 sink (pre-update x)
            x = (x + x1 + sg0 * x2) * q;
        }
        a = x; a64 = z;
    };

    // Exact pow2 rescale from a previously-sampled exponent (r5-proven).
    auto scale = [&](int eb) {
        e_total += eb - 127;
        const float inv = __uint_as_float((unsigned)(254 - eb) << 23);  // 2^-e
        a *= inv; a64 *= inv;
    };

    float Q[2][4];
    ldsq(Q[0], 0); ldsq(Q[1], 1);
    int ebp = sample_eb(a);

    // Groups 0..62 (recursion rows 1..252), register double-buffer PFG=2.
#pragma clang loop unroll(disable)
    for (int g = 0; g < 63; ++g) {
        group4(Q[g & 1]);
        scale(ebp);
        ebp = sample_eb(a);
        if (g + 2 < 63) ldsq(Q[g & 1], g + 2);
    }

    // Recursion rows 253..255, single steps (no rescale; r9-identical).
#pragma unroll
    for (int r = 0; r < 3; ++r) {
        const float qo = table[trow(253 + r)][slot];
        const float p1 = wshr1(a);
        const float p2 = wshr1(p1);
        const float qb = wshr1(qo);
        const float an = (a + p1 + sg0 * p2) * (qo + EPSF);
        a64 = (a64 + a) * (qb + EPSF);
        a = an;
    }
    // Both waves now hold alpha after 256 rows (fwd: rows 0..255;
    // rev: rows 511..256 of the reversed problem).

    if (w == 1) {
        shR[lane] = a;                 // alpha'[state lane], states 0..63
        if (lane == 63) shR[64] = a64; // alpha'[64]
        if (lane == 0)  shE = e_total;
    }
    __syncthreads();

    if (w == 0) {
        // Pre-emission predecessor sum for target state s2 = lane.
        const float a1 = wshr1(a);
        const float a2 = wshr1(a1);
        const float abar = a + a1 + sg0 * a2;
        // Junction dot-product in DOUBLE: halves are independently
        // normalized; matched terms can be ~2^-136 (f32 flushes -> inf).
        double p = (double)abar * (double)shR[64 - lane];
        if (lane == 63) p += (double)(a64 + a) * (double)shR[0];
#pragma unroll
        for (int m = 1; m < 64; m <<= 1) p += __shfl(p, lane ^ m);
        if (lane == 0) {
            if (p < 1e-300) p = 1e-300;            // guard (never hit in range)
            const unsigned long long bt = __double_as_longlong(p);
            const int k = (int)((bt >> 52) & 0x7FFULL) - 1023;
            const double mant = __longlong_as_double(
                (bt & 0x000FFFFFFFFFFFFFULL) | 0x3FF0000000000000ULL);  // [1,2)
            out[b] = -(__logf((float)mant) +
                       (float)(e_total + shE + k) * 0.6931471805599453f);
        }
    }
}

extern "C" void kernel_launch(void* const* d_in, const int* in_sizes, int n_in,
                              void* d_out, int out_size, void* d_ws, size_t ws_size,
                              hipStream_t stream) {
    const int*   y_true = (const int*)d_in[0];
    const float* y_pred = (const float*)d_in[1];
    float*       out    = (float*)d_out;

    const int B = out_size;   // output is [B,1]
    ctc_loss_kernel<<<B, 128, 0, stream>>>(y_true, y_pred, out);
}